// Round 9
// baseline (204.511 us; speedup 1.0000x reference)
//
#include <hip/hip_runtime.h>
#include <hip/hip_bf16.h>
#include <math.h>

// B=4, T=4096, D=1024, H=4, d=64. Inputs FP32. OUTPUT BUFFER IS FP32.
// Outputs concatenated fp32: y [4,4096,1024] at 0, kv_f [4,4,64,64] at
// 16777216 floats, kc_f [4,4,64] after.
// d_out y region (64MB) doubles as scratch: qkv bf16 [0,25.2MB),
// Xb bf16 [25.2MB,58.7MB), Wb bf16 [58.7MB,60.3MB). All overwritten by
// gemm_out last (which reads only d_ws + fp32 inputs -> no race).
// d_ws: cs fp32 17.04MB + yatt bf16 8.39MB = 25.4MB.
// R3: qkv stores phi(q), phi(k); feature map fused into gemm_qkv epilogue.
// R5/R6: gemm_out pure-bf16 gl_lds GEMM (WoB via convert_wo). 196.0us.
// R7/R8: 128^2 pipeline variants -- null. Diagnosis: at 128^2 the per-K-tile
// MFMA phase is ~80cy/SIMD vs ~450cy L3 latency -> no prefetch depth at this
// tile can hide loads. Fix = bigger tile, not deeper prefetch.
// R9: gemm_qkv -> 256x256/BK=64/8-wave, 2-deep counted-vmcnt (m201 geometry):
// compute/K-tile ~640cy/SIMD > 450cy latency -> depth-2 hides fully.
// Sync per tile: {frag ds_reads + 64 MFMA} lgkm0+sbar; STAGE t+2 -> buf c
// (8 gl_lds, clamped); vmcnt(8)+sbar (tile t+1 resident: own oldest 8 done,
// then block-wide agree). Bijective XCD swizzle (192=8*24): each XCD gets 8
// contiguous row-panels (4MB A-set ~= L2). Accumulation order per element
// unchanged -> bit-identical output.
#define T_SEQ   4096
#define NB      4
#define NH      4
#define DH      64
#define DM      1024
#define MR      16384
#define NQKV    768
#define CH      64
#define NCH     64
#define SST     4160       // per-chunk state floats: 64*64 + 64
#define BHN     16

typedef __attribute__((ext_vector_type(4))) float          f32x4;
typedef __attribute__((ext_vector_type(8))) short          s16x8;
typedef __attribute__((ext_vector_type(4))) unsigned short u16x4;

__device__ __forceinline__ float bf2f(unsigned short u) {
  union { unsigned int i; float f; } c; c.i = ((unsigned int)u) << 16; return c.f;
}
__device__ __forceinline__ unsigned short f2bf(float f) {
  union { float f; unsigned int i; } c; c.f = f;
  unsigned int i = c.i;
  return (unsigned short)((i + 0x7fffu + ((i >> 16) & 1u)) >> 16);  // RNE
}
__device__ __forceinline__ s16x8 pack8(f32x4 lo, f32x4 hi) {
  s16x8 r;
  r[0] = (short)f2bf(lo.x); r[1] = (short)f2bf(lo.y);
  r[2] = (short)f2bf(lo.z); r[3] = (short)f2bf(lo.w);
  r[4] = (short)f2bf(hi.x); r[5] = (short)f2bf(hi.y);
  r[6] = (short)f2bf(hi.z); r[7] = (short)f2bf(hi.w);
  return r;
}
// async global->LDS, 16B per lane. LDS dest must be (wave-uniform + lane*16).
__device__ __forceinline__ void gl_lds16(const unsigned short* g, unsigned short* l) {
  __builtin_amdgcn_global_load_lds(
      (const __attribute__((address_space(1))) unsigned int*)g,
      (__attribute__((address_space(3))) unsigned int*)l, 16, 0, 0);
}

// ---------------------------------------------------------------------------
// Pass 0: fp32 -> bf16 conversion of X and concat(Wq,Wk,Wv). Memory-bound.
// ---------------------------------------------------------------------------
__global__ __launch_bounds__(256) void convert_kernel(
    const float* __restrict__ X,
    const float* __restrict__ Wq, const float* __restrict__ Wk,
    const float* __restrict__ Wv,
    unsigned short* __restrict__ Xb, unsigned short* __restrict__ Wb)
{
  const long long NX = 16777216LL;        // 16384*1024
  const long long NW = 786432LL;          // 3*256*1024
  const long long total = NX + NW;
  const long long stride = (long long)gridDim.x * 256 * 8;
  for (long long i = ((long long)blockIdx.x * 256 + threadIdx.x) * 8;
       i < total; i += stride) {
    const float* src;
    unsigned short* dst;
    if (i < NX) { src = X + i; dst = Xb + i; }
    else {
      const long long e = i - NX;
      const int w = (int)(e >> 18);                   // 262144 per weight
      const long long rr = e & 262143LL;
      src = (w == 0 ? Wq : w == 1 ? Wk : Wv) + rr;
      dst = Wb + e;
    }
    const f32x4 lo = *(const f32x4*)src;
    const f32x4 hi = *(const f32x4*)(src + 4);
    *(s16x8*)dst = pack8(lo, hi);
  }
}

// ---------------------------------------------------------------------------
// Pass 4.5: Wo fp32 -> bf16 into the cs region of d_ws (dead after
// chunk_out). Launched between chunk_out and gemm_out. 1024*256 elems.
// ---------------------------------------------------------------------------
__global__ __launch_bounds__(256) void convert_wo_kernel(
    const float* __restrict__ Wo, unsigned short* __restrict__ WoB)
{
  const int i = (blockIdx.x * 256 + threadIdx.x) * 8;   // grid covers exactly
  const f32x4 lo = *(const f32x4*)(Wo + i);
  const f32x4 hi = *(const f32x4*)(Wo + i + 4);
  *(s16x8*)(WoB + i) = pack8(lo, hi);
}

// ---------------------------------------------------------------------------
// GEMM 1 (R9): qkv[16384,768] = phi(Xb*Wb^T). 256x256 tile, BK=64, 512 thr
// = 8 waves (2Mx4N), per-wave C = 128x64 (acc[8][4] f32x4). LDS: full A/B
// double buffers, XOR-swizzled (elem-group g at row r holds global group
// g^(r&7); involution). 2-deep counted-vmcnt pipeline; see file header.
// Epilogue fuses phi for Q/K col-blocks (bn<2): each wave's 64-col span is
// one head -> row L2-norm via shfl_xor{1,2,4,8} across the l16 group.
// ---------------------------------------------------------------------------
__global__ __launch_bounds__(512, 2) void gemm_qkv_kernel(
    const unsigned short* __restrict__ Xb,
    const unsigned short* __restrict__ Wb,
    unsigned short* __restrict__ C)
{
  constexpr int K = DM;       // 1024
  constexpr int N = NQKV;     // 768
  __shared__ __align__(16) unsigned short sA[2][256 * 64];   // 32KB each
  __shared__ __align__(16) unsigned short sB[2][256 * 64];   // total 128KB

  const int tid  = threadIdx.x;
  const int wave = tid >> 6;          // 0..7
  const int lane = tid & 63;
  const int quad = lane >> 4;
  const int l16  = lane & 15;
  const int wr = (wave >> 2) * 128;   // wave row offset: 0/128
  const int wc = (wave & 3) * 64;     // wave col offset: 0/64/128/192

  // bijective XCD swizzle: 192 WGs = 8 XCDs x 24; XCD k gets bx in [8k,8k+8)
  const int orig = blockIdx.x;
  const int swz  = (orig & 7) * 24 + (orig >> 3);
  const int bx   = swz / 3;
  const int bn   = swz % 3;           // 0=Q, 1=K, 2=V col-block of 256
  const int row0 = bx * 256;

  const unsigned short* Ab = Xb + (size_t)row0 * K;
  const unsigned short* Bb = Wb + (size_t)(bn * 256) * K;

  // staging geometry: pass p covers rows [p*64, p*64+64); thread stages
  // row srow=tid/8, group sg=tid%7.. (tid&7); src col = (sg^(srow&7))*8.
  const int srow = tid >> 3;          // 0..63
  const int sg   = tid & 7;
  const int ssc  = (sg ^ (srow & 7)) << 3;

  f32x4 acc[8][4];
  #pragma unroll
  for (int i = 0; i < 8; i++)
    #pragma unroll
    for (int j = 0; j < 4; j++) acc[i][j] = (f32x4){0.f, 0.f, 0.f, 0.f};

#define STAGE_QKV(c, kt)                                                      \
  {                                                                           \
    _Pragma("unroll")                                                         \
    for (int p = 0; p < 4; p++)                                               \
      gl_lds16(Ab + (size_t)(p * 64 + srow) * K + (kt) + ssc,                 \
               &sA[c][p * 4096 + tid * 8]);                                   \
    _Pragma("unroll")                                                         \
    for (int p = 0; p < 4; p++)                                               \
      gl_lds16(Bb + (size_t)(p * 64 + srow) * K + (kt) + ssc,                 \
               &sB[c][p * 4096 + tid * 8]);                                   \
  }

  // prologue: tiles 0,1 in flight (16 loads); wait oldest 8 (tile 0).
  STAGE_QKV(0, 0);
  STAGE_QKV(1, 64);
  asm volatile("s_waitcnt vmcnt(8)" ::: "memory");
  __builtin_amdgcn_sched_barrier(0);
  __builtin_amdgcn_s_barrier();

  int cur = 0;
  for (int kt = 0; kt < K; kt += 64) {
    // B fragments for the whole tile (4 j x 2 ks)
    s16x8 bwf[4][2];
    #pragma unroll
    for (int j = 0; j < 4; j++)
      #pragma unroll
      for (int ks = 0; ks < 2; ks++) {
        const int r = wc + j * 16 + l16;
        bwf[j][ks] = *(const s16x8*)(&sB[cur][r * 64 + (((ks * 4 + quad) ^ (r & 7)) << 3)]);
      }
    // 4 phases x (4 A-frag reads + 16 MFMA); compiler inserts lgkmcnt.
    __builtin_amdgcn_s_setprio(1);
    #pragma unroll
    for (int ph = 0; ph < 4; ph++) {
      s16x8 afp[2][2];
      #pragma unroll
      for (int ii = 0; ii < 2; ii++)
        #pragma unroll
        for (int ks = 0; ks < 2; ks++) {
          const int r = wr + (ph * 2 + ii) * 16 + l16;
          afp[ii][ks] = *(const s16x8*)(&sA[cur][r * 64 + (((ks * 4 + quad) ^ (r & 7)) << 3)]);
        }
      #pragma unroll
      for (int ii = 0; ii < 2; ii++)
        #pragma unroll
        for (int j = 0; j < 4; j++) {
          acc[ph * 2 + ii][j] = __builtin_amdgcn_mfma_f32_16x16x32_bf16(
              afp[ii][0], bwf[j][0], acc[ph * 2 + ii][j], 0, 0, 0);
          acc[ph * 2 + ii][j] = __builtin_amdgcn_mfma_f32_16x16x32_bf16(
              afp[ii][1], bwf[j][1], acc[ph * 2 + ii][j], 0, 0, 0);
        }
    }
    __builtin_amdgcn_s_setprio(0);
    // all ds_reads of buf cur consumed; drain + block-wide agree
    asm volatile("s_waitcnt lgkmcnt(0)" ::: "memory");
    __builtin_amdgcn_sched_barrier(0);
    __builtin_amdgcn_s_barrier();
    // prefetch tile kt+128 into buf cur (clamped tail keeps count uniform)
    const int ktp = (kt + 128 < K) ? (kt + 128) : (K - 64);
    STAGE_QKV(cur, ktp);
    // tile kt+64 resident: own oldest 8 retired, then all waves agree
    asm volatile("s_waitcnt vmcnt(8)" ::: "memory");
    __builtin_amdgcn_sched_barrier(0);
    __builtin_amdgcn_s_barrier();
    cur ^= 1;
  }
#undef STAGE_QKV

  const int colb = bn * 256 + wc;
  if (bn < 2) {
    // phi(x)=elu(x)+1, unit-L2 over the head (this wave's 64 cols).
    #pragma unroll
    for (int i = 0; i < 8; i++) {
      const int r = row0 + wr + i * 16 + quad * 4;
      #pragma unroll
      for (int g = 0; g < 4; g++) {
        float p[4];
        float ss = 0.f;
        #pragma unroll
        for (int j = 0; j < 4; j++) {
          const float a = acc[i][j][g];
          p[j] = a > 0.f ? a + 1.f : __expf(a);
          ss += p[j] * p[j];
        }
        ss += __shfl_xor(ss, 1, 64);
        ss += __shfl_xor(ss, 2, 64);
        ss += __shfl_xor(ss, 4, 64);
        ss += __shfl_xor(ss, 8, 64);
        const float inv = 1.f / (sqrtf(ss) + 1e-6f);
        #pragma unroll
        for (int j = 0; j < 4; j++)
          C[(size_t)(r + g) * N + colb + j * 16 + l16] = f2bf(p[j] * inv);
      }
    }
  } else {
    #pragma unroll
    for (int i = 0; i < 8; i++) {
      const int r = row0 + wr + i * 16 + quad * 4;
      #pragma unroll
      for (int j = 0; j < 4; j++) {
        const int cc = colb + j * 16 + l16;
        #pragma unroll
        for (int g = 0; g < 4; g++)
          C[(size_t)(r + g) * N + cc] = f2bf(acc[i][j][g]);
      }
    }
  }
}

// ---------------------------------------------------------------------------
// GEMM 2: Out[16384,1024] FP32 = yatt[16384,256]bf16 * WoB^T (bf16).
// R6-verified: both operands via global_load_lds, 16KB LDS, zero staging
// VALU; fp32 epilogue store. UNCHANGED.
// ---------------------------------------------------------------------------
__global__ __launch_bounds__(256, 2) void gemm_out_kernel(
    const unsigned short* __restrict__ Y,
    const unsigned short* __restrict__ WoB,
    float* __restrict__ Out)
{
  constexpr int K = 256;
  constexpr int N = DM;
  __shared__ __align__(16) unsigned short sA[128 * 32];
  __shared__ __align__(16) unsigned short sB[128 * 32];

  const int tid  = threadIdx.x;
  const int wave = tid >> 6;
  const int lane = tid & 63;
  const int quad = lane >> 4;
  const int l16  = lane & 15;
  const int wm = (wave >> 1) * 64;
  const int wn = (wave & 1) * 64;

  const int row0  = blockIdx.x * 128;
  const int bcol0 = blockIdx.y * 128;

  const int srow = tid >> 2;
  const int scol = ((tid & 3) ^ (srow & 3)) * 8;
  const unsigned short* Ag = Y   + (size_t)(row0  + srow) * K + scol;
  const unsigned short* Bg = WoB + (size_t)(bcol0 + srow) * K + scol;
  unsigned short* sAp = sA + tid * 8;
  unsigned short* sBp = sB + tid * 8;

  const int ra = (quad ^ (l16 & 3)) * 8;

  f32x4 acc[4][4];
  #pragma unroll
  for (int i = 0; i < 4; i++)
    #pragma unroll
    for (int j = 0; j < 4; j++) acc[i][j] = (f32x4){0.f, 0.f, 0.f, 0.f};

  for (int kt = 0; kt < K; kt += 32) {
    __syncthreads();
    gl_lds16(Ag + kt,                  sAp);
    gl_lds16(Ag + kt + (size_t)64 * K, sAp + 2048);
    gl_lds16(Bg + kt,                  sBp);
    gl_lds16(Bg + kt + (size_t)64 * K, sBp + 2048);
    __syncthreads();
    s16x8 af[4], bw[4];
    #pragma unroll
    for (int i = 0; i < 4; i++)
      af[i] = *(const s16x8*)(sA + (wm + i * 16 + l16) * 32 + ra);
    #pragma unroll
    for (int j = 0; j < 4; j++)
      bw[j] = *(const s16x8*)(sB + (wn + j * 16 + l16) * 32 + ra);
    #pragma unroll
    for (int i = 0; i < 4; i++)
      #pragma unroll
      for (int j = 0; j < 4; j++)
        acc[i][j] = __builtin_amdgcn_mfma_f32_16x16x32_bf16(af[i], bw[j], acc[i][j], 0, 0, 0);
  }

  #pragma unroll
  for (int i = 0; i < 4; i++) {
    const int r = row0 + wm + i * 16 + quad * 4;
    #pragma unroll
    for (int j = 0; j < 4; j++) {
      const int cc = bcol0 + wn + j * 16 + l16;
      #pragma unroll
      for (int g = 0; g < 4; g++)
        Out[(size_t)(r + g) * N + cc] = acc[i][j][g];   // fp32 store
    }
  }
}

// ---------------------------------------------------------------------------
// Pass 1: per-chunk KV state S[dd][j] = sum_t phi_k[t][dd]*v[t][j] -> 64x64x64
// MFMA GEMM (contraction over t). phi already applied upstream: staging is
// pure pass-through (K^T, V^T bf16, XOR-swizzled). ksum via fp32 partials.
// ---------------------------------------------------------------------------
__global__ __launch_bounds__(256) void chunk_sums_kernel(
    const unsigned short* __restrict__ qkv,
    float* __restrict__ cs)          // [BHN*NCH][SST]
{
  const int blk = blockIdx.x;        // bh*NCH + c
  const int bh = blk >> 6, c = blk & 63;
  const int b = bh >> 2, h = bh & 3;
  __shared__ __align__(16) unsigned short sKt[64 * 64];  // K^T [dd][t] swz
  __shared__ __align__(16) unsigned short sVt[64 * 64];  // V^T [j][t]  swz
  __shared__ float sPart[4 * 64];
  const int wave = threadIdx.x >> 6, lane = threadIdx.x & 63;
  const int quad = lane >> 4, l16 = lane & 15;
  const size_t rowbase = ((size_t)b * T_SEQ + (size_t)c * CH) * NQKV + h * DH;

  float kacc = 0.f;
  #pragma unroll 4
  for (int tt = 0; tt < 16; tt++) {
    const int t = tt * 4 + wave;
    const unsigned short* r = qkv + rowbase + (size_t)t * NQKV;
    const unsigned short ku = r[256 + lane];
    const unsigned short vu = r[512 + lane];
    kacc += bf2f(ku);
    const int sw = (lane & 7) << 3;
    sKt[lane * 64 + (t ^ sw)] = ku;         // K^T: row=dd(=lane), col=t
    sVt[lane * 64 + (t ^ sw)] = vu;         // V^T: row=j (=lane), col=t
  }
  sPart[wave * 64 + lane] = kacc;
  __syncthreads();

  const int wr = (wave >> 1) * 32;   // dd offset
  const int wc = (wave & 1) * 32;    // j offset
  f32x4 acc[2][2];
  #pragma unroll
  for (int i = 0; i < 2; i++)
    #pragma unroll
    for (int j = 0; j < 2; j++) acc[i][j] = (f32x4){0.f, 0.f, 0.f, 0.f};

  #pragma unroll
  for (int ks = 0; ks < 2; ks++) {       // contraction over t (2 x K=32)
    const int grp = ks * 4 + quad;
    s16x8 ak[2], bv[2];
    #pragma unroll
    for (int i = 0; i < 2; i++) {
      const int rk = wr + i * 16 + l16;
      ak[i] = *(const s16x8*)(sKt + rk * 64 + ((grp ^ (rk & 7)) << 3));
    }
    #pragma unroll
    for (int j = 0; j < 2; j++) {
      const int rj = wc + j * 16 + l16;
      bv[j] = *(const s16x8*)(sVt + rj * 64 + ((grp ^ (rj & 7)) << 3));
    }
    #pragma unroll
    for (int i = 0; i < 2; i++)
      #pragma unroll
      for (int j = 0; j < 2; j++)
        acc[i][j] = __builtin_amdgcn_mfma_f32_16x16x32_bf16(ak[i], bv[j], acc[i][j], 0, 0, 0);
  }

  float* o = cs + (size_t)blk * SST;
  #pragma unroll
  for (int i = 0; i < 2; i++)
    #pragma unroll
    for (int j = 0; j < 2; j++)
      #pragma unroll
      for (int g = 0; g < 4; g++) {
        const int dd = wr + i * 16 + quad * 4 + g;
        const int jj = wc + j * 16 + l16;
        o[dd * 64 + jj] = acc[i][j][g];
      }
  if (threadIdx.x < 64)
    o[4096 + threadIdx.x] = sPart[threadIdx.x] + sPart[64 + threadIdx.x]
                          + sPart[128 + threadIdx.x] + sPart[192 + threadIdx.x];
}

// ---------------------------------------------------------------------------
// Pass 2: exclusive prefix scan over chunks, in-place. Emits kv_f, kc_f as
// FP32 to the output tail (float offsets!).
// ---------------------------------------------------------------------------
__global__ __launch_bounds__(256) void scan_kernel(
    float* __restrict__ cs, float* __restrict__ outTail)
{
  const int gid = blockIdx.x * 256 + threadIdx.x;   // BHN*SST threads
  const int bh = gid / SST;
  const int e  = gid - bh * SST;
  float run = 0.f;
  size_t idx = (size_t)bh * NCH * SST + e;
  for (int c = 0; c < NCH; c++, idx += SST) {
    const float v = cs[idx];
    cs[idx] = run;
    run += v;
  }
  if (e < 4096) {          // kv_f[b,h,j,dd] = state[dd][j] (transpose)
    const int dd = e >> 6, j = e & 63;
    outTail[(size_t)bh * 4096 + j * 64 + dd] = run;
  } else {                 // kc_f[b,h,dd]
    const int dd = e - 4096;
    outTail[BHN * 4096 + (size_t)bh * 64 + dd] = run;
  }
}

// ---------------------------------------------------------------------------
// Pass 3 (MFMA): per-chunk outputs. phi already applied upstream.
//   A   = tril(Q K^T)                       -> phase A MFMA, masked, bf16 LDS
//   num = Q @ S0 + A @ V                    -> phase B MFMA (one accumulator)
//   den = q . kc0 + rowsum(tril A) + eps    -> cheap VALU pass from bf16 A
//   y_att = num/den -> bf16 [MR][256]
// Q,K staged via global_load_lds (pre-swizzled source col, linear dest ->
// identical LDS image to the old register path). V^T register transpose.
// ---------------------------------------------------------------------------
__global__ __launch_bounds__(256, 4) void chunk_out_kernel(
    const unsigned short* __restrict__ qkv,
    const float* __restrict__ st,
    unsigned short* __restrict__ yatt)
{
  const int blk = blockIdx.x;
  const int bh = blk >> 6;
  const int c  = blk & 63;
  const int b = bh >> 2, h = bh & 3;

  __shared__ __align__(16) unsigned short sQ [64 * 64];  // Q  [t][d]  bf16 swz
  __shared__ __align__(16) unsigned short sKA[64 * 64];  // K  [s][d], then A [t][s]
  __shared__ __align__(16) unsigned short sVt[64 * 64];  // V^T[j][t]  bf16 swz
  __shared__ __align__(16) unsigned short sSt[64 * 64];  // S^T[j][d]  bf16 swz
  __shared__ float sKc[64];
  __shared__ float sDen[64];

  const int tid  = threadIdx.x;
  const int wave = tid >> 6, lane = tid & 63;
  const int quad = lane >> 4, l16 = lane & 15;
  const size_t rowbase = ((size_t)b * T_SEQ + (size_t)c * CH) * NQKV + h * DH;

  // ---- stage: Q,K async via global_load_lds (2 passes each) ----
  #pragma unroll
  for (int p = 0; p < 2; p++) {
    const int e  = p * 2048 + tid * 8;       // dest elem (linear = swz layout)
    const int t  = e >> 6;
    const int c0 = e & 56;                   // 8-aligned col within row
    const int sc = c0 ^ ((t & 7) << 3);      // source col (involution)
    const unsigned short* src = qkv + rowbase + (size_t)t * NQKV + sc;
    gl_lds16(src,       sQ  + e);
    gl_lds16(src + 256, sKA + e);
  }
  // ---- V^T register transpose (pass-through bf16) ----
  #pragma unroll 4
  for (int tt = 0; tt < 16; tt++) {
    const int t = tt * 4 + wave;
    sVt[lane * 64 + (t ^ ((lane & 7) << 3))] =
        qkv[rowbase + (size_t)t * NQKV + 512 + lane];
  }
  // state S[d][j] fp32 -> sSt[j][d] bf16 (transposed, swizzled); kc fp32
  const float* stp = st + (size_t)blk * SST;
  for (int i = tid; i < 1024; i += 256) {
    const f32x4 s4 = ((const f32x4*)stp)[i];
    const int d = i >> 4, j0 = (i & 15) << 2;
    #pragma unroll
    for (int g = 0; g < 4; g++) {
      const int j = j0 + g;
      sSt[j * 64 + (d ^ ((j & 7) << 3))] = f2bf(s4[g]);
    }
  }
  if (tid < 64) sKc[tid] = stp[4096 + tid];
  __syncthreads();   // drains vmcnt (gl_lds) + lgkmcnt

  // wave -> 32x32 output quadrant
  const int wr = (wave >> 1) * 32;   // t offset
  const int wc = (wave & 1) * 32;    // s / j offset

  // ---- phase A: A = Q K^T (contraction over d) ----
  f32x4 accA[2][2];
  #pragma unroll
  for (int i = 0; i < 2; i++)
    #pragma unroll
    for (int j = 0; j < 2; j++) accA[i][j] = (f32x4){0.f, 0.f, 0.f, 0.f};

  #pragma unroll
  for (int ks = 0; ks < 2; ks++) {
    const int grp = ks * 4 + quad;
    s16x8 aq[2], bk[2];
    #pragma unroll
    for (int i = 0; i < 2; i++) {
      const int rq = wr + i * 16 + l16;
      aq[i] = *(const s16x8*)(sQ + rq * 64 + ((grp ^ (rq & 7)) << 3));
    }
    #pragma unroll
    for (int j = 0; j < 2; j++) {
      const int rk = wc + j * 16 + l16;
      bk[j] = *(const s16x8*)(sKA + rk * 64 + ((grp ^ (rk & 7)) << 3));
    }
    #pragma unroll
    for (int i = 0; i < 2; i++)
      #pragma unroll
      for (int j = 0; j < 2; j++)
        accA[i][j] = __builtin_amdgcn_mfma_f32_16x16x32_bf16(aq[i], bk[j], accA[i][j], 0, 0, 0);
  }
  __syncthreads();   // all waves done reading K -> safe to overwrite with A

  // causal mask + store A (bf16, swizzled) into sKA
  #pragma unroll
  for (int i = 0; i < 2; i++)
    #pragma unroll
    for (int j = 0; j < 2; j++)
      #pragma unroll
      for (int g = 0; g < 4; g++) {
        const int t = wr + i * 16 + quad * 4 + g;
        const int s = wc + j * 16 + l16;
        const float av = (s <= t) ? accA[i][j][g] : 0.f;
        sKA[t * 64 + (s ^ ((t & 7) << 3))] = f2bf(av);
      }
  __syncthreads();

  // ---- den[t] = q.kc + rowsum(tril A) + eps (4 threads per row) ----
  {
    const int t = tid >> 2, p = tid & 3;
    const int sw = (t & 7) << 3;
    float s = 0.f;
    #pragma unroll
    for (int e = 0; e < 16; e++) {
      const int d = p * 16 + e;
      s += bf2f(sKA[t * 64 + d]);                      // swizzle is a row permutation
      s += bf2f(sQ[t * 64 + (d ^ sw)]) * sKc[d];
    }
    s += __shfl_xor(s, 1, 64);
    s += __shfl_xor(s, 2, 64);
    if (p == 0) sDen[t] = s + 1e-6f;
  }
  __syncthreads();

  // ---- phase B: num = Q @ S^T^T + A @ V^T^T (one accumulator) ----
  f32x4 acc[2][2];
  #pragma unroll
  for (int i = 0; i < 2; i++)
    #pragma unroll
    for (int j = 0; j < 2; j++) acc[i][j] = (f32x4){0.f, 0.f, 0.f, 0.f};

  #pragma unroll
  for (int ks = 0; ks < 2; ks++) {        // B1: contraction over d
    const int grp = ks * 4 + quad;
    s16x8 aq[2], bs[2];
    #pragma unroll
    for (int i = 0; i < 2; i++) {
      const int rq = wr + i * 16 + l16;
      aq[i] = *(const s16x8*)(sQ + rq * 64 + ((grp ^ (rq & 7)) << 3));
    }
    #pragma unroll
    for (int j = 0; j < 2; j++) {
      const int rj = wc + j * 16 + l16;
      bs[j] = *(const s16x8*)(sSt + rj * 64 + ((grp ^ (rj & 7)) << 3));
    }
    #pragma unroll
    for (int i = 0; i < 2; i++)
      #pragma unroll
      for (int j = 0; j < 2; j++)
        acc[i][j] = __builtin_amdgcn_mfma_f32_16x16x32_bf16(aq[i], bs[j], acc[i][j], 0, 0, 0);
  }
  #pragma unroll
  for (int ks = 0; ks < 2; ks++) {        // B2: contraction over s
    const int grp = ks * 4 + quad;
    s16x8 aa[2], bv[2];
    #pragma unroll
    for (int i = 0; i < 2; i++) {
      const int rt = wr + i * 16 + l16;
      aa[i] = *(const s16x8*)(sKA + rt * 64 + ((grp ^ (rt & 7)) << 3));
    }
    #pragma unroll
    for (int j = 0; j < 2; j++) {
      const int rj = wc + j * 16 + l16;
      bv[j] = *(const s16x8*)(sVt + rj * 64 + ((grp ^ (rj & 7)) << 3));
    }
    #pragma unroll
    for (int i = 0; i < 2; i++)
      #pragma unroll
      for (int j = 0; j < 2; j++)
        acc[i][j] = __builtin_amdgcn_mfma_f32_16x16x32_bf16(aa[i], bv[j], acc[i][j], 0, 0, 0);
  }

  // ---- epilogue: y = num / den -> bf16 ----
  #pragma unroll
  for (int i = 0; i < 2; i++)
    #pragma unroll
    for (int g = 0; g < 4; g++) {
      const int t = wr + i * 16 + quad * 4 + g;
      const float inv = 1.f / sDen[t];
      #pragma unroll
      for (int j = 0; j < 2; j++) {
        const int jj = wc + j * 16 + l16;
        const size_t o = ((size_t)b * T_SEQ + (size_t)c * CH + t) * 256 + h * 64 + jj;
        yatt[o] = f2bf(acc[i][j][g] * inv);
      }
    }
}

// ---------------------------------------------------------------------------
extern "C" void kernel_launch(void* const* d_in, const int* in_sizes, int n_in,
                              void* d_out, int out_size, void* d_ws, size_t ws_size,
                              hipStream_t stream) {
  const float* X  = (const float*)d_in[0];
  const float* Wq = (const float*)d_in[1];
  const float* Wk = (const float*)d_in[2];
  const float* Wv = (const float*)d_in[3];
  const float* Wo = (const float*)d_in[4];
  float* out = (float*)d_out;                        // FP32 output buffer

  // scratch parked inside d_out's fp32 y region (64MB), overwritten by
  // gemm_out last (gemm_out reads only d_ws -> no race):
  unsigned short* qkvb = (unsigned short*)d_out;                          // 25.2MB
  unsigned short* Xb   = (unsigned short*)((char*)d_out + 25165824ull);   // 32MB
  unsigned short* Wb   = Xb + 16777216;                                   // 1.5MB
  float* outTail = out + 16777216;                   // kv_f then kc_f (fp32)
  float*          cs   = (float*)d_ws;               // 17.04MB
  unsigned short* yatt = (unsigned short*)((char*)d_ws + 17039360ull);  // 8.39MB
  // WoB (bf16 Wo, 512KB) reuses the cs region -- dead after chunk_out.
  unsigned short* WoB  = (unsigned short*)d_ws;

  convert_kernel   <<<4096,         256, 0, stream>>>(X, Wq, Wk, Wv, Xb, Wb);
  gemm_qkv_kernel  <<<192,          512, 0, stream>>>(Xb, Wb, qkvb);
  chunk_sums_kernel<<<BHN * NCH,    256, 0, stream>>>(qkvb, cs);
  scan_kernel      <<<(BHN * SST) / 256, 256, 0, stream>>>(cs, outTail);
  chunk_out_kernel <<<BHN * NCH,    256, 0, stream>>>(qkvb, cs, yatt);
  convert_wo_kernel<<<128,          256, 0, stream>>>(Wo, WoB);
  gemm_out_kernel  <<<dim3(128, 8), 256, 0, stream>>>(yatt, WoB, out);
}

// Round 10
// 192.796 us; speedup vs baseline: 1.0608x; 1.0608x over previous
//
#include <hip/hip_runtime.h>
#include <hip/hip_bf16.h>
#include <math.h>

// B=4, T=4096, D=1024, H=4, d=64. Inputs FP32. OUTPUT BUFFER IS FP32.
// Outputs concatenated fp32: y [4,4096,1024] at 0, kv_f [4,4,64,64] at
// 16777216 floats, kc_f [4,4,64] after.
// d_out y region (64MB) doubles as scratch: qkv bf16 [0,25.2MB),
// Xb bf16 [25.2MB,58.7MB), Wb bf16 [58.7MB,60.3MB). All overwritten by
// gemm_out last (which reads only d_ws + fp32 inputs -> no race).
// d_ws: cs fp32 17.04MB + yatt bf16 8.39MB = 25.4MB.
// R3: qkv stores phi(q), phi(k); feature map fused into gemm_qkv epilogue.
// R5/R6: gemm_out pure-bf16 gl_lds GEMM (WoB via convert_wo). 196.0us.
// R7/R8: 128^2 pipeline variants -- null (barrier drains vmcnt; 80cy compute
// can't hide 450cy latency). R9: 256^2 coarse phase-split -- REGRESSED
// (m196's documented anti-pattern; 1 blk/CU, 192 WGs < 256 CUs).
// R10: revert to R6's verified stage->barrier->compute structure, BK 32->64:
// halves the barrier/drain count, doubles MFMA per drain, LDS 32KB single
// buffer (grid-limited 3 blk/CU unchanged). Same sync pattern as verified;
// per-element MFMA order unchanged -> bit-identical output.
#define T_SEQ   4096
#define NB      4
#define NH      4
#define DH      64
#define DM      1024
#define MR      16384
#define NQKV    768
#define CH      64
#define NCH     64
#define SST     4160       // per-chunk state floats: 64*64 + 64
#define BHN     16

typedef __attribute__((ext_vector_type(4))) float          f32x4;
typedef __attribute__((ext_vector_type(8))) short          s16x8;
typedef __attribute__((ext_vector_type(4))) unsigned short u16x4;

__device__ __forceinline__ float bf2f(unsigned short u) {
  union { unsigned int i; float f; } c; c.i = ((unsigned int)u) << 16; return c.f;
}
__device__ __forceinline__ unsigned short f2bf(float f) {
  union { float f; unsigned int i; } c; c.f = f;
  unsigned int i = c.i;
  return (unsigned short)((i + 0x7fffu + ((i >> 16) & 1u)) >> 16);  // RNE
}
__device__ __forceinline__ s16x8 pack8(f32x4 lo, f32x4 hi) {
  s16x8 r;
  r[0] = (short)f2bf(lo.x); r[1] = (short)f2bf(lo.y);
  r[2] = (short)f2bf(lo.z); r[3] = (short)f2bf(lo.w);
  r[4] = (short)f2bf(hi.x); r[5] = (short)f2bf(hi.y);
  r[6] = (short)f2bf(hi.z); r[7] = (short)f2bf(hi.w);
  return r;
}
// async global->LDS, 16B per lane. LDS dest must be (wave-uniform + lane*16).
__device__ __forceinline__ void gl_lds16(const unsigned short* g, unsigned short* l) {
  __builtin_amdgcn_global_load_lds(
      (const __attribute__((address_space(1))) unsigned int*)g,
      (__attribute__((address_space(3))) unsigned int*)l, 16, 0, 0);
}

// ---------------------------------------------------------------------------
// Pass 0: fp32 -> bf16 conversion of X and concat(Wq,Wk,Wv). Memory-bound.
// ---------------------------------------------------------------------------
__global__ __launch_bounds__(256) void convert_kernel(
    const float* __restrict__ X,
    const float* __restrict__ Wq, const float* __restrict__ Wk,
    const float* __restrict__ Wv,
    unsigned short* __restrict__ Xb, unsigned short* __restrict__ Wb)
{
  const long long NX = 16777216LL;        // 16384*1024
  const long long NW = 786432LL;          // 3*256*1024
  const long long total = NX + NW;
  const long long stride = (long long)gridDim.x * 256 * 8;
  for (long long i = ((long long)blockIdx.x * 256 + threadIdx.x) * 8;
       i < total; i += stride) {
    const float* src;
    unsigned short* dst;
    if (i < NX) { src = X + i; dst = Xb + i; }
    else {
      const long long e = i - NX;
      const int w = (int)(e >> 18);                   // 262144 per weight
      const long long rr = e & 262143LL;
      src = (w == 0 ? Wq : w == 1 ? Wk : Wv) + rr;
      dst = Wb + e;
    }
    const f32x4 lo = *(const f32x4*)src;
    const f32x4 hi = *(const f32x4*)(src + 4);
    *(s16x8*)dst = pack8(lo, hi);
  }
}

// ---------------------------------------------------------------------------
// Pass 4.5: Wo fp32 -> bf16 into the cs region of d_ws (dead after
// chunk_out). Launched between chunk_out and gemm_out. 1024*256 elems.
// ---------------------------------------------------------------------------
__global__ __launch_bounds__(256) void convert_wo_kernel(
    const float* __restrict__ Wo, unsigned short* __restrict__ WoB)
{
  const int i = (blockIdx.x * 256 + threadIdx.x) * 8;   // grid covers exactly
  const f32x4 lo = *(const f32x4*)(Wo + i);
  const f32x4 hi = *(const f32x4*)(Wo + i + 4);
  *(s16x8*)(WoB + i) = pack8(lo, hi);
}

// ---------------------------------------------------------------------------
// GEMM 1 (R10): qkv[16384,768] = phi(Xb*Wb^T). 128x128 tile, 4 waves, BK=64:
// per K-step stage A/B 128x64 (8 gl_lds/thread, pre-swizzled source cols,
// linear LDS dest), two barriers, 16 ds_read_b128 frags + 32 MFMA per wave.
// Same verified sync structure as R6, half the K-steps.
// Epilogue fuses phi for Q/K blocks (bn<4): each wave's 64-col span is one
// head -> row L2-norm via shfl_xor{1,2,4,8} across the l16 group.
// ---------------------------------------------------------------------------
__global__ __launch_bounds__(256, 2) void gemm_qkv_kernel(
    const unsigned short* __restrict__ Xb,
    const unsigned short* __restrict__ Wb,
    unsigned short* __restrict__ C)
{
  constexpr int K = DM;
  constexpr int N = NQKV;
  __shared__ __align__(16) unsigned short sA[128 * 64];   // 16KB
  __shared__ __align__(16) unsigned short sB[128 * 64];   // 16KB

  const int tid  = threadIdx.x;
  const int wave = tid >> 6;
  const int lane = tid & 63;
  const int quad = lane >> 4;
  const int l16  = lane & 15;
  const int wm = (wave >> 1) * 64;
  const int wn = (wave & 1) * 64;

  const int row0 = blockIdx.x * 128;
  const int bn   = blockIdx.y;                 // 0..5
  // staging: round p covers rows [p*32, p*32+32); thread stages row
  // srow = p*32 + (tid>>3), stored group g0 = tid&7 holds source group
  // g0^(srow&7)  (involution; read side applies the same XOR).
  const int sr8 = tid >> 3;                    // 0..31 row-within-round
  const int sg  = tid & 7;
  const unsigned short* Ab = Xb + (size_t)(row0     ) * K;
  const unsigned short* Bb = Wb + (size_t)(bn * 128 ) * K;

  f32x4 acc[4][4];
  #pragma unroll
  for (int i = 0; i < 4; i++)
    #pragma unroll
    for (int j = 0; j < 4; j++) acc[i][j] = (f32x4){0.f, 0.f, 0.f, 0.f};

  for (int kt = 0; kt < K; kt += 64) {
    __syncthreads();
    #pragma unroll
    for (int p = 0; p < 4; p++) {
      const int r   = p * 32 + sr8;
      const int sc  = (sg ^ (r & 7)) << 3;     // pre-swizzled source col
      gl_lds16(Ab + (size_t)r * K + kt + sc, sA + p * 2048 + tid * 8);
      gl_lds16(Bb + (size_t)r * K + kt + sc, sB + p * 2048 + tid * 8);
    }
    __syncthreads();                            // drains vmcnt: tile resident
    s16x8 af[4][2], bw[4][2];
    #pragma unroll
    for (int i = 0; i < 4; i++)
      #pragma unroll
      for (int ks = 0; ks < 2; ks++) {
        const int r = wm + i * 16 + l16;
        af[i][ks] = *(const s16x8*)(sA + r * 64 + (((ks * 4 + quad) ^ (r & 7)) << 3));
      }
    #pragma unroll
    for (int j = 0; j < 4; j++)
      #pragma unroll
      for (int ks = 0; ks < 2; ks++) {
        const int r = wn + j * 16 + l16;
        bw[j][ks] = *(const s16x8*)(sB + r * 64 + (((ks * 4 + quad) ^ (r & 7)) << 3));
      }
    #pragma unroll
    for (int i = 0; i < 4; i++)
      #pragma unroll
      for (int j = 0; j < 4; j++) {
        acc[i][j] = __builtin_amdgcn_mfma_f32_16x16x32_bf16(af[i][0], bw[j][0], acc[i][j], 0, 0, 0);
        acc[i][j] = __builtin_amdgcn_mfma_f32_16x16x32_bf16(af[i][1], bw[j][1], acc[i][j], 0, 0, 0);
      }
  }

  const int colb = bn * 128 + wn;
  if (bn < 4) {
    // phi(x)=elu(x)+1, unit-L2 over the head (this wave's 64 cols).
    #pragma unroll
    for (int i = 0; i < 4; i++) {
      const int r = row0 + wm + i * 16 + quad * 4;
      #pragma unroll
      for (int g = 0; g < 4; g++) {
        float p[4];
        float ss = 0.f;
        #pragma unroll
        for (int j = 0; j < 4; j++) {
          const float a = acc[i][j][g];
          p[j] = a > 0.f ? a + 1.f : __expf(a);
          ss += p[j] * p[j];
        }
        ss += __shfl_xor(ss, 1, 64);
        ss += __shfl_xor(ss, 2, 64);
        ss += __shfl_xor(ss, 4, 64);
        ss += __shfl_xor(ss, 8, 64);
        const float inv = 1.f / (sqrtf(ss) + 1e-6f);
        #pragma unroll
        for (int j = 0; j < 4; j++)
          C[(size_t)(r + g) * N + colb + j * 16 + l16] = f2bf(p[j] * inv);
      }
    }
  } else {
    #pragma unroll
    for (int i = 0; i < 4; i++) {
      const int r = row0 + wm + i * 16 + quad * 4;
      #pragma unroll
      for (int j = 0; j < 4; j++) {
        const int cc = colb + j * 16 + l16;
        #pragma unroll
        for (int g = 0; g < 4; g++)
          C[(size_t)(r + g) * N + cc] = f2bf(acc[i][j][g]);
      }
    }
  }
}

// ---------------------------------------------------------------------------
// GEMM 2: Out[16384,1024] FP32 = yatt[16384,256]bf16 * WoB^T (bf16).
// R6-verified: both operands via global_load_lds, 16KB LDS, zero staging
// VALU; fp32 epilogue store. UNCHANGED.
// ---------------------------------------------------------------------------
__global__ __launch_bounds__(256, 2) void gemm_out_kernel(
    const unsigned short* __restrict__ Y,
    const unsigned short* __restrict__ WoB,
    float* __restrict__ Out)
{
  constexpr int K = 256;
  constexpr int N = DM;
  __shared__ __align__(16) unsigned short sA[128 * 32];
  __shared__ __align__(16) unsigned short sB[128 * 32];

  const int tid  = threadIdx.x;
  const int wave = tid >> 6;
  const int lane = tid & 63;
  const int quad = lane >> 4;
  const int l16  = lane & 15;
  const int wm = (wave >> 1) * 64;
  const int wn = (wave & 1) * 64;

  const int row0  = blockIdx.x * 128;
  const int bcol0 = blockIdx.y * 128;

  const int srow = tid >> 2;
  const int scol = ((tid & 3) ^ (srow & 3)) * 8;
  const unsigned short* Ag = Y   + (size_t)(row0  + srow) * K + scol;
  const unsigned short* Bg = WoB + (size_t)(bcol0 + srow) * K + scol;
  unsigned short* sAp = sA + tid * 8;
  unsigned short* sBp = sB + tid * 8;

  const int ra = (quad ^ (l16 & 3)) * 8;

  f32x4 acc[4][4];
  #pragma unroll
  for (int i = 0; i < 4; i++)
    #pragma unroll
    for (int j = 0; j < 4; j++) acc[i][j] = (f32x4){0.f, 0.f, 0.f, 0.f};

  for (int kt = 0; kt < K; kt += 32) {
    __syncthreads();
    gl_lds16(Ag + kt,                  sAp);
    gl_lds16(Ag + kt + (size_t)64 * K, sAp + 2048);
    gl_lds16(Bg + kt,                  sBp);
    gl_lds16(Bg + kt + (size_t)64 * K, sBp + 2048);
    __syncthreads();
    s16x8 af[4], bw[4];
    #pragma unroll
    for (int i = 0; i < 4; i++)
      af[i] = *(const s16x8*)(sA + (wm + i * 16 + l16) * 32 + ra);
    #pragma unroll
    for (int j = 0; j < 4; j++)
      bw[j] = *(const s16x8*)(sB + (wn + j * 16 + l16) * 32 + ra);
    #pragma unroll
    for (int i = 0; i < 4; i++)
      #pragma unroll
      for (int j = 0; j < 4; j++)
        acc[i][j] = __builtin_amdgcn_mfma_f32_16x16x32_bf16(af[i], bw[j], acc[i][j], 0, 0, 0);
  }

  #pragma unroll
  for (int i = 0; i < 4; i++) {
    const int r = row0 + wm + i * 16 + quad * 4;
    #pragma unroll
    for (int j = 0; j < 4; j++) {
      const int cc = bcol0 + wn + j * 16 + l16;
      #pragma unroll
      for (int g = 0; g < 4; g++)
        Out[(size_t)(r + g) * N + cc] = acc[i][j][g];   // fp32 store
    }
  }
}

// ---------------------------------------------------------------------------
// Pass 1: per-chunk KV state S[dd][j] = sum_t phi_k[t][dd]*v[t][j] -> 64x64x64
// MFMA GEMM (contraction over t). phi already applied upstream: staging is
// pure pass-through (K^T, V^T bf16, XOR-swizzled). ksum via fp32 partials.
// ---------------------------------------------------------------------------
__global__ __launch_bounds__(256) void chunk_sums_kernel(
    const unsigned short* __restrict__ qkv,
    float* __restrict__ cs)          // [BHN*NCH][SST]
{
  const int blk = blockIdx.x;        // bh*NCH + c
  const int bh = blk >> 6, c = blk & 63;
  const int b = bh >> 2, h = bh & 3;
  __shared__ __align__(16) unsigned short sKt[64 * 64];  // K^T [dd][t] swz
  __shared__ __align__(16) unsigned short sVt[64 * 64];  // V^T [j][t]  swz
  __shared__ float sPart[4 * 64];
  const int wave = threadIdx.x >> 6, lane = threadIdx.x & 63;
  const int quad = lane >> 4, l16 = lane & 15;
  const size_t rowbase = ((size_t)b * T_SEQ + (size_t)c * CH) * NQKV + h * DH;

  float kacc = 0.f;
  #pragma unroll 4
  for (int tt = 0; tt < 16; tt++) {
    const int t = tt * 4 + wave;
    const unsigned short* r = qkv + rowbase + (size_t)t * NQKV;
    const unsigned short ku = r[256 + lane];
    const unsigned short vu = r[512 + lane];
    kacc += bf2f(ku);
    const int sw = (lane & 7) << 3;
    sKt[lane * 64 + (t ^ sw)] = ku;         // K^T: row=dd(=lane), col=t
    sVt[lane * 64 + (t ^ sw)] = vu;         // V^T: row=j (=lane), col=t
  }
  sPart[wave * 64 + lane] = kacc;
  __syncthreads();

  const int wr = (wave >> 1) * 32;   // dd offset
  const int wc = (wave & 1) * 32;    // j offset
  f32x4 acc[2][2];
  #pragma unroll
  for (int i = 0; i < 2; i++)
    #pragma unroll
    for (int j = 0; j < 2; j++) acc[i][j] = (f32x4){0.f, 0.f, 0.f, 0.f};

  #pragma unroll
  for (int ks = 0; ks < 2; ks++) {       // contraction over t (2 x K=32)
    const int grp = ks * 4 + quad;
    s16x8 ak[2], bv[2];
    #pragma unroll
    for (int i = 0; i < 2; i++) {
      const int rk = wr + i * 16 + l16;
      ak[i] = *(const s16x8*)(sKt + rk * 64 + ((grp ^ (rk & 7)) << 3));
    }
    #pragma unroll
    for (int j = 0; j < 2; j++) {
      const int rj = wc + j * 16 + l16;
      bv[j] = *(const s16x8*)(sVt + rj * 64 + ((grp ^ (rj & 7)) << 3));
    }
    #pragma unroll
    for (int i = 0; i < 2; i++)
      #pragma unroll
      for (int j = 0; j < 2; j++)
        acc[i][j] = __builtin_amdgcn_mfma_f32_16x16x32_bf16(ak[i], bv[j], acc[i][j], 0, 0, 0);
  }

  float* o = cs + (size_t)blk * SST;
  #pragma unroll
  for (int i = 0; i < 2; i++)
    #pragma unroll
    for (int j = 0; j < 2; j++)
      #pragma unroll
      for (int g = 0; g < 4; g++) {
        const int dd = wr + i * 16 + quad * 4 + g;
        const int jj = wc + j * 16 + l16;
        o[dd * 64 + jj] = acc[i][j][g];
      }
  if (threadIdx.x < 64)
    o[4096 + threadIdx.x] = sPart[threadIdx.x] + sPart[64 + threadIdx.x]
                          + sPart[128 + threadIdx.x] + sPart[192 + threadIdx.x];
}

// ---------------------------------------------------------------------------
// Pass 2: exclusive prefix scan over chunks, in-place. Emits kv_f, kc_f as
// FP32 to the output tail (float offsets!).
// ---------------------------------------------------------------------------
__global__ __launch_bounds__(256) void scan_kernel(
    float* __restrict__ cs, float* __restrict__ outTail)
{
  const int gid = blockIdx.x * 256 + threadIdx.x;   // BHN*SST threads
  const int bh = gid / SST;
  const int e  = gid - bh * SST;
  float run = 0.f;
  size_t idx = (size_t)bh * NCH * SST + e;
  for (int c = 0; c < NCH; c++, idx += SST) {
    const float v = cs[idx];
    cs[idx] = run;
    run += v;
  }
  if (e < 4096) {          // kv_f[b,h,j,dd] = state[dd][j] (transpose)
    const int dd = e >> 6, j = e & 63;
    outTail[(size_t)bh * 4096 + j * 64 + dd] = run;
  } else {                 // kc_f[b,h,dd]
    const int dd = e - 4096;
    outTail[BHN * 4096 + (size_t)bh * 64 + dd] = run;
  }
}

// ---------------------------------------------------------------------------
// Pass 3 (MFMA): per-chunk outputs. phi already applied upstream.
//   A   = tril(Q K^T)                       -> phase A MFMA, masked, bf16 LDS
//   num = Q @ S0 + A @ V                    -> phase B MFMA (one accumulator)
//   den = q . kc0 + rowsum(tril A) + eps    -> cheap VALU pass from bf16 A
//   y_att = num/den -> bf16 [MR][256]
// Q,K staged via global_load_lds (pre-swizzled source col, linear dest ->
// identical LDS image to the old register path). V^T register transpose.
// ---------------------------------------------------------------------------
__global__ __launch_bounds__(256, 4) void chunk_out_kernel(
    const unsigned short* __restrict__ qkv,
    const float* __restrict__ st,
    unsigned short* __restrict__ yatt)
{
  const int blk = blockIdx.x;
  const int bh = blk >> 6;
  const int c  = blk & 63;
  const int b = bh >> 2, h = bh & 3;

  __shared__ __align__(16) unsigned short sQ [64 * 64];  // Q  [t][d]  bf16 swz
  __shared__ __align__(16) unsigned short sKA[64 * 64];  // K  [s][d], then A [t][s]
  __shared__ __align__(16) unsigned short sVt[64 * 64];  // V^T[j][t]  bf16 swz
  __shared__ __align__(16) unsigned short sSt[64 * 64];  // S^T[j][d]  bf16 swz
  __shared__ float sKc[64];
  __shared__ float sDen[64];

  const int tid  = threadIdx.x;
  const int wave = tid >> 6, lane = tid & 63;
  const int quad = lane >> 4, l16 = lane & 15;
  const size_t rowbase = ((size_t)b * T_SEQ + (size_t)c * CH) * NQKV + h * DH;

  // ---- stage: Q,K async via global_load_lds (2 passes each) ----
  #pragma unroll
  for (int p = 0; p < 2; p++) {
    const int e  = p * 2048 + tid * 8;       // dest elem (linear = swz layout)
    const int t  = e >> 6;
    const int c0 = e & 56;                   // 8-aligned col within row
    const int sc = c0 ^ ((t & 7) << 3);      // source col (involution)
    const unsigned short* src = qkv + rowbase + (size_t)t * NQKV + sc;
    gl_lds16(src,       sQ  + e);
    gl_lds16(src + 256, sKA + e);
  }
  // ---- V^T register transpose (pass-through bf16) ----
  #pragma unroll 4
  for (int tt = 0; tt < 16; tt++) {
    const int t = tt * 4 + wave;
    sVt[lane * 64 + (t ^ ((lane & 7) << 3))] =
        qkv[rowbase + (size_t)t * NQKV + 512 + lane];
  }
  // state S[d][j] fp32 -> sSt[j][d] bf16 (transposed, swizzled); kc fp32
  const float* stp = st + (size_t)blk * SST;
  for (int i = tid; i < 1024; i += 256) {
    const f32x4 s4 = ((const f32x4*)stp)[i];
    const int d = i >> 4, j0 = (i & 15) << 2;
    #pragma unroll
    for (int g = 0; g < 4; g++) {
      const int j = j0 + g;
      sSt[j * 64 + (d ^ ((j & 7) << 3))] = f2bf(s4[g]);
    }
  }
  if (tid < 64) sKc[tid] = stp[4096 + tid];
  __syncthreads();   // drains vmcnt (gl_lds) + lgkmcnt

  // wave -> 32x32 output quadrant
  const int wr = (wave >> 1) * 32;   // t offset
  const int wc = (wave & 1) * 32;    // s / j offset

  // ---- phase A: A = Q K^T (contraction over d) ----
  f32x4 accA[2][2];
  #pragma unroll
  for (int i = 0; i < 2; i++)
    #pragma unroll
    for (int j = 0; j < 2; j++) accA[i][j] = (f32x4){0.f, 0.f, 0.f, 0.f};

  #pragma unroll
  for (int ks = 0; ks < 2; ks++) {
    const int grp = ks * 4 + quad;
    s16x8 aq[2], bk[2];
    #pragma unroll
    for (int i = 0; i < 2; i++) {
      const int rq = wr + i * 16 + l16;
      aq[i] = *(const s16x8*)(sQ + rq * 64 + ((grp ^ (rq & 7)) << 3));
    }
    #pragma unroll
    for (int j = 0; j < 2; j++) {
      const int rk = wc + j * 16 + l16;
      bk[j] = *(const s16x8*)(sKA + rk * 64 + ((grp ^ (rk & 7)) << 3));
    }
    #pragma unroll
    for (int i = 0; i < 2; i++)
      #pragma unroll
      for (int j = 0; j < 2; j++)
        accA[i][j] = __builtin_amdgcn_mfma_f32_16x16x32_bf16(aq[i], bk[j], accA[i][j], 0, 0, 0);
  }
  __syncthreads();   // all waves done reading K -> safe to overwrite with A

  // causal mask + store A (bf16, swizzled) into sKA
  #pragma unroll
  for (int i = 0; i < 2; i++)
    #pragma unroll
    for (int j = 0; j < 2; j++)
      #pragma unroll
      for (int g = 0; g < 4; g++) {
        const int t = wr + i * 16 + quad * 4 + g;
        const int s = wc + j * 16 + l16;
        const float av = (s <= t) ? accA[i][j][g] : 0.f;
        sKA[t * 64 + (s ^ ((t & 7) << 3))] = f2bf(av);
      }
  __syncthreads();

  // ---- den[t] = q.kc + rowsum(tril A) + eps (4 threads per row) ----
  {
    const int t = tid >> 2, p = tid & 3;
    const int sw = (t & 7) << 3;
    float s = 0.f;
    #pragma unroll
    for (int e = 0; e < 16; e++) {
      const int d = p * 16 + e;
      s += bf2f(sKA[t * 64 + d]);                      // swizzle is a row permutation
      s += bf2f(sQ[t * 64 + (d ^ sw)]) * sKc[d];
    }
    s += __shfl_xor(s, 1, 64);
    s += __shfl_xor(s, 2, 64);
    if (p == 0) sDen[t] = s + 1e-6f;
  }
  __syncthreads();

  // ---- phase B: num = Q @ S^T^T + A @ V^T^T (one accumulator) ----
  f32x4 acc[2][2];
  #pragma unroll
  for (int i = 0; i < 2; i++)
    #pragma unroll
    for (int j = 0; j < 2; j++) acc[i][j] = (f32x4){0.f, 0.f, 0.f, 0.f};

  #pragma unroll
  for (int ks = 0; ks < 2; ks++) {        // B1: contraction over d
    const int grp = ks * 4 + quad;
    s16x8 aq[2], bs[2];
    #pragma unroll
    for (int i = 0; i < 2; i++) {
      const int rq = wr + i * 16 + l16;
      aq[i] = *(const s16x8*)(sQ + rq * 64 + ((grp ^ (rq & 7)) << 3));
    }
    #pragma unroll
    for (int j = 0; j < 2; j++) {
      const int rj = wc + j * 16 + l16;
      bs[j] = *(const s16x8*)(sSt + rj * 64 + ((grp ^ (rj & 7)) << 3));
    }
    #pragma unroll
    for (int i = 0; i < 2; i++)
      #pragma unroll
      for (int j = 0; j < 2; j++)
        acc[i][j] = __builtin_amdgcn_mfma_f32_16x16x32_bf16(aq[i], bs[j], acc[i][j], 0, 0, 0);
  }
  #pragma unroll
  for (int ks = 0; ks < 2; ks++) {        // B2: contraction over s
    const int grp = ks * 4 + quad;
    s16x8 aa[2], bv[2];
    #pragma unroll
    for (int i = 0; i < 2; i++) {
      const int rt = wr + i * 16 + l16;
      aa[i] = *(const s16x8*)(sKA + rt * 64 + ((grp ^ (rt & 7)) << 3));
    }
    #pragma unroll
    for (int j = 0; j < 2; j++) {
      const int rj = wc + j * 16 + l16;
      bv[j] = *(const s16x8*)(sVt + rj * 64 + ((grp ^ (rj & 7)) << 3));
    }
    #pragma unroll
    for (int i = 0; i < 2; i++)
      #pragma unroll
      for (int j = 0; j < 2; j++)
        acc[i][j] = __builtin_amdgcn_mfma_f32_16x16x32_bf16(aa[i], bv[j], acc[i][j], 0, 0, 0);
  }

  // ---- epilogue: y = num / den -> bf16 ----
  #pragma unroll
  for (int i = 0; i < 2; i++)
    #pragma unroll
    for (int g = 0; g < 4; g++) {
      const int t = wr + i * 16 + quad * 4 + g;
      const float inv = 1.f / sDen[t];
      #pragma unroll
      for (int j = 0; j < 2; j++) {
        const int jj = wc + j * 16 + l16;
        const size_t o = ((size_t)b * T_SEQ + (size_t)c * CH + t) * 256 + h * 64 + jj;
        yatt[o] = f2bf(acc[i][j][g] * inv);
      }
    }
}

// ---------------------------------------------------------------------------
extern "C" void kernel_launch(void* const* d_in, const int* in_sizes, int n_in,
                              void* d_out, int out_size, void* d_ws, size_t ws_size,
                              hipStream_t stream) {
  const float* X  = (const float*)d_in[0];
  const float* Wq = (const float*)d_in[1];
  const float* Wk = (const float*)d_in[2];
  const float* Wv = (const float*)d_in[3];
  const float* Wo = (const float*)d_in[4];
  float* out = (float*)d_out;                        // FP32 output buffer

  // scratch parked inside d_out's fp32 y region (64MB), overwritten by
  // gemm_out last (gemm_out reads only d_ws -> no race):
  unsigned short* qkvb = (unsigned short*)d_out;                          // 25.2MB
  unsigned short* Xb   = (unsigned short*)((char*)d_out + 25165824ull);   // 32MB
  unsigned short* Wb   = Xb + 16777216;                                   // 1.5MB
  float* outTail = out + 16777216;                   // kv_f then kc_f (fp32)
  float*          cs   = (float*)d_ws;               // 17.04MB
  unsigned short* yatt = (unsigned short*)((char*)d_ws + 17039360ull);  // 8.39MB
  // WoB (bf16 Wo, 512KB) reuses the cs region -- dead after chunk_out.
  unsigned short* WoB  = (unsigned short*)d_ws;

  convert_kernel   <<<4096,         256, 0, stream>>>(X, Wq, Wk, Wv, Xb, Wb);
  gemm_qkv_kernel  <<<dim3(128, 6), 256, 0, stream>>>(Xb, Wb, qkvb);
  chunk_sums_kernel<<<BHN * NCH,    256, 0, stream>>>(qkvb, cs);
  scan_kernel      <<<(BHN * SST) / 256, 256, 0, stream>>>(cs, outTail);
  chunk_out_kernel <<<BHN * NCH,    256, 0, stream>>>(qkvb, cs, yatt);
  convert_wo_kernel<<<128,          256, 0, stream>>>(Wo, WoB);
  gemm_out_kernel  <<<dim3(128, 8), 256, 0, stream>>>(yatt, WoB, out);
}

// Round 11
// 190.249 us; speedup vs baseline: 1.0750x; 1.0134x over previous
//
#include <hip/hip_runtime.h>
#include <hip/hip_bf16.h>
#include <math.h>

// B=4, T=4096, D=1024, H=4, d=64. Inputs FP32. OUTPUT BUFFER IS FP32.
// Outputs concatenated fp32: y [4,4096,1024] at 0, kv_f [4,4,64,64] at
// 16777216 floats, kc_f [4,4,64] after.
// d_out y region (64MB) doubles as scratch: qkv bf16 [0,25.2MB),
// Xb bf16 [25.2MB,58.7MB), Wb bf16 [58.7MB,60.3MB). All overwritten by
// gemm_out last (which reads only d_ws + fp32 inputs -> no race).
// d_ws: cs fp32 17.04MB + yatt bf16 8.39MB = 25.4MB.
// R3: qkv stores phi(q), phi(k); feature map fused into gemm_qkv epilogue.
// R5/R6: gemm_out pure-bf16 gl_lds GEMM (WoB via convert_wo). 196.0us.
// R7/R8: 128^2 pipeline variants -- null. R9: 256^2 coarse split -- regressed.
// R10: gemm_qkv BK 32->64 (same verified sync pattern, half the barrier
// drains) -- WIN, 192.8us.
// R11: same BK=64 transplant to gemm_out (K=256: 8->4 K-steps, 16->8
// barriers). Per-element MFMA order still k-ascending -> bit-identical.
#define T_SEQ   4096
#define NB      4
#define NH      4
#define DH      64
#define DM      1024
#define MR      16384
#define NQKV    768
#define CH      64
#define NCH     64
#define SST     4160       // per-chunk state floats: 64*64 + 64
#define BHN     16

typedef __attribute__((ext_vector_type(4))) float          f32x4;
typedef __attribute__((ext_vector_type(8))) short          s16x8;
typedef __attribute__((ext_vector_type(4))) unsigned short u16x4;

__device__ __forceinline__ float bf2f(unsigned short u) {
  union { unsigned int i; float f; } c; c.i = ((unsigned int)u) << 16; return c.f;
}
__device__ __forceinline__ unsigned short f2bf(float f) {
  union { float f; unsigned int i; } c; c.f = f;
  unsigned int i = c.i;
  return (unsigned short)((i + 0x7fffu + ((i >> 16) & 1u)) >> 16);  // RNE
}
__device__ __forceinline__ s16x8 pack8(f32x4 lo, f32x4 hi) {
  s16x8 r;
  r[0] = (short)f2bf(lo.x); r[1] = (short)f2bf(lo.y);
  r[2] = (short)f2bf(lo.z); r[3] = (short)f2bf(lo.w);
  r[4] = (short)f2bf(hi.x); r[5] = (short)f2bf(hi.y);
  r[6] = (short)f2bf(hi.z); r[7] = (short)f2bf(hi.w);
  return r;
}
// async global->LDS, 16B per lane. LDS dest must be (wave-uniform + lane*16).
__device__ __forceinline__ void gl_lds16(const unsigned short* g, unsigned short* l) {
  __builtin_amdgcn_global_load_lds(
      (const __attribute__((address_space(1))) unsigned int*)g,
      (__attribute__((address_space(3))) unsigned int*)l, 16, 0, 0);
}

// ---------------------------------------------------------------------------
// Pass 0: fp32 -> bf16 conversion of X and concat(Wq,Wk,Wv). Memory-bound.
// ---------------------------------------------------------------------------
__global__ __launch_bounds__(256) void convert_kernel(
    const float* __restrict__ X,
    const float* __restrict__ Wq, const float* __restrict__ Wk,
    const float* __restrict__ Wv,
    unsigned short* __restrict__ Xb, unsigned short* __restrict__ Wb)
{
  const long long NX = 16777216LL;        // 16384*1024
  const long long NW = 786432LL;          // 3*256*1024
  const long long total = NX + NW;
  const long long stride = (long long)gridDim.x * 256 * 8;
  for (long long i = ((long long)blockIdx.x * 256 + threadIdx.x) * 8;
       i < total; i += stride) {
    const float* src;
    unsigned short* dst;
    if (i < NX) { src = X + i; dst = Xb + i; }
    else {
      const long long e = i - NX;
      const int w = (int)(e >> 18);                   // 262144 per weight
      const long long rr = e & 262143LL;
      src = (w == 0 ? Wq : w == 1 ? Wk : Wv) + rr;
      dst = Wb + e;
    }
    const f32x4 lo = *(const f32x4*)src;
    const f32x4 hi = *(const f32x4*)(src + 4);
    *(s16x8*)dst = pack8(lo, hi);
  }
}

// ---------------------------------------------------------------------------
// Pass 4.5: Wo fp32 -> bf16 into the cs region of d_ws (dead after
// chunk_out). Launched between chunk_out and gemm_out. 1024*256 elems.
// ---------------------------------------------------------------------------
__global__ __launch_bounds__(256) void convert_wo_kernel(
    const float* __restrict__ Wo, unsigned short* __restrict__ WoB)
{
  const int i = (blockIdx.x * 256 + threadIdx.x) * 8;   // grid covers exactly
  const f32x4 lo = *(const f32x4*)(Wo + i);
  const f32x4 hi = *(const f32x4*)(Wo + i + 4);
  *(s16x8*)(WoB + i) = pack8(lo, hi);
}

// ---------------------------------------------------------------------------
// GEMM 1 (R10, verified): qkv[16384,768] = phi(Xb*Wb^T). 128x128 tile,
// 4 waves, BK=64: per K-step stage A/B 128x64 (8 gl_lds/thread, pre-swizzled
// source cols, linear LDS dest), two barriers, 16 ds_read_b128 + 32 MFMA/wave.
// Epilogue fuses phi for Q/K blocks (bn<4).
// ---------------------------------------------------------------------------
__global__ __launch_bounds__(256, 2) void gemm_qkv_kernel(
    const unsigned short* __restrict__ Xb,
    const unsigned short* __restrict__ Wb,
    unsigned short* __restrict__ C)
{
  constexpr int K = DM;
  constexpr int N = NQKV;
  __shared__ __align__(16) unsigned short sA[128 * 64];   // 16KB
  __shared__ __align__(16) unsigned short sB[128 * 64];   // 16KB

  const int tid  = threadIdx.x;
  const int wave = tid >> 6;
  const int lane = tid & 63;
  const int quad = lane >> 4;
  const int l16  = lane & 15;
  const int wm = (wave >> 1) * 64;
  const int wn = (wave & 1) * 64;

  const int row0 = blockIdx.x * 128;
  const int bn   = blockIdx.y;                 // 0..5
  const int sr8 = tid >> 3;                    // 0..31 row-within-round
  const int sg  = tid & 7;
  const unsigned short* Ab = Xb + (size_t)(row0     ) * K;
  const unsigned short* Bb = Wb + (size_t)(bn * 128 ) * K;

  f32x4 acc[4][4];
  #pragma unroll
  for (int i = 0; i < 4; i++)
    #pragma unroll
    for (int j = 0; j < 4; j++) acc[i][j] = (f32x4){0.f, 0.f, 0.f, 0.f};

  for (int kt = 0; kt < K; kt += 64) {
    __syncthreads();
    #pragma unroll
    for (int p = 0; p < 4; p++) {
      const int r   = p * 32 + sr8;
      const int sc  = (sg ^ (r & 7)) << 3;     // pre-swizzled source col
      gl_lds16(Ab + (size_t)r * K + kt + sc, sA + p * 2048 + tid * 8);
      gl_lds16(Bb + (size_t)r * K + kt + sc, sB + p * 2048 + tid * 8);
    }
    __syncthreads();                            // drains vmcnt: tile resident
    s16x8 af[4][2], bw[4][2];
    #pragma unroll
    for (int i = 0; i < 4; i++)
      #pragma unroll
      for (int ks = 0; ks < 2; ks++) {
        const int r = wm + i * 16 + l16;
        af[i][ks] = *(const s16x8*)(sA + r * 64 + (((ks * 4 + quad) ^ (r & 7)) << 3));
      }
    #pragma unroll
    for (int j = 0; j < 4; j++)
      #pragma unroll
      for (int ks = 0; ks < 2; ks++) {
        const int r = wn + j * 16 + l16;
        bw[j][ks] = *(const s16x8*)(sB + r * 64 + (((ks * 4 + quad) ^ (r & 7)) << 3));
      }
    #pragma unroll
    for (int i = 0; i < 4; i++)
      #pragma unroll
      for (int j = 0; j < 4; j++) {
        acc[i][j] = __builtin_amdgcn_mfma_f32_16x16x32_bf16(af[i][0], bw[j][0], acc[i][j], 0, 0, 0);
        acc[i][j] = __builtin_amdgcn_mfma_f32_16x16x32_bf16(af[i][1], bw[j][1], acc[i][j], 0, 0, 0);
      }
  }

  const int colb = bn * 128 + wn;
  if (bn < 4) {
    // phi(x)=elu(x)+1, unit-L2 over the head (this wave's 64 cols).
    #pragma unroll
    for (int i = 0; i < 4; i++) {
      const int r = row0 + wm + i * 16 + quad * 4;
      #pragma unroll
      for (int g = 0; g < 4; g++) {
        float p[4];
        float ss = 0.f;
        #pragma unroll
        for (int j = 0; j < 4; j++) {
          const float a = acc[i][j][g];
          p[j] = a > 0.f ? a + 1.f : __expf(a);
          ss += p[j] * p[j];
        }
        ss += __shfl_xor(ss, 1, 64);
        ss += __shfl_xor(ss, 2, 64);
        ss += __shfl_xor(ss, 4, 64);
        ss += __shfl_xor(ss, 8, 64);
        const float inv = 1.f / (sqrtf(ss) + 1e-6f);
        #pragma unroll
        for (int j = 0; j < 4; j++)
          C[(size_t)(r + g) * N + colb + j * 16 + l16] = f2bf(p[j] * inv);
      }
    }
  } else {
    #pragma unroll
    for (int i = 0; i < 4; i++) {
      const int r = row0 + wm + i * 16 + quad * 4;
      #pragma unroll
      for (int j = 0; j < 4; j++) {
        const int cc = colb + j * 16 + l16;
        #pragma unroll
        for (int g = 0; g < 4; g++)
          C[(size_t)(r + g) * N + cc] = f2bf(acc[i][j][g]);
      }
    }
  }
}

// ---------------------------------------------------------------------------
// GEMM 2 (R11): Out[16384,1024] FP32 = yatt[16384,256]bf16 * WoB^T (bf16).
// BK=64 transplant of the R10-verified pattern: K=256 -> 4 K-steps, 8
// barriers (was 16). LDS 32KB, occupancy grid-limited 4 blk/CU. Per-element
// MFMA order k-ascending -> bit-identical to R6.
// ---------------------------------------------------------------------------
__global__ __launch_bounds__(256, 2) void gemm_out_kernel(
    const unsigned short* __restrict__ Y,
    const unsigned short* __restrict__ WoB,
    float* __restrict__ Out)
{
  constexpr int K = 256;
  constexpr int N = DM;
  __shared__ __align__(16) unsigned short sA[128 * 64];   // 16KB
  __shared__ __align__(16) unsigned short sB[128 * 64];   // 16KB

  const int tid  = threadIdx.x;
  const int wave = tid >> 6;
  const int lane = tid & 63;
  const int quad = lane >> 4;
  const int l16  = lane & 15;
  const int wm = (wave >> 1) * 64;
  const int wn = (wave & 1) * 64;

  const int row0  = blockIdx.x * 128;
  const int bcol0 = blockIdx.y * 128;

  const int sr8 = tid >> 3;                    // 0..31 row-within-round
  const int sg  = tid & 7;
  const unsigned short* Ab = Y   + (size_t)row0  * K;
  const unsigned short* Bb = WoB + (size_t)bcol0 * K;

  f32x4 acc[4][4];
  #pragma unroll
  for (int i = 0; i < 4; i++)
    #pragma unroll
    for (int j = 0; j < 4; j++) acc[i][j] = (f32x4){0.f, 0.f, 0.f, 0.f};

  for (int kt = 0; kt < K; kt += 64) {
    __syncthreads();
    #pragma unroll
    for (int p = 0; p < 4; p++) {
      const int r   = p * 32 + sr8;
      const int sc  = (sg ^ (r & 7)) << 3;     // pre-swizzled source col
      gl_lds16(Ab + (size_t)r * K + kt + sc, sA + p * 2048 + tid * 8);
      gl_lds16(Bb + (size_t)r * K + kt + sc, sB + p * 2048 + tid * 8);
    }
    __syncthreads();                            // drains vmcnt: tile resident
    s16x8 af[4][2], bw[4][2];
    #pragma unroll
    for (int i = 0; i < 4; i++)
      #pragma unroll
      for (int ks = 0; ks < 2; ks++) {
        const int r = wm + i * 16 + l16;
        af[i][ks] = *(const s16x8*)(sA + r * 64 + (((ks * 4 + quad) ^ (r & 7)) << 3));
      }
    #pragma unroll
    for (int j = 0; j < 4; j++)
      #pragma unroll
      for (int ks = 0; ks < 2; ks++) {
        const int r = wn + j * 16 + l16;
        bw[j][ks] = *(const s16x8*)(sB + r * 64 + (((ks * 4 + quad) ^ (r & 7)) << 3));
      }
    #pragma unroll
    for (int i = 0; i < 4; i++)
      #pragma unroll
      for (int j = 0; j < 4; j++) {
        acc[i][j] = __builtin_amdgcn_mfma_f32_16x16x32_bf16(af[i][0], bw[j][0], acc[i][j], 0, 0, 0);
        acc[i][j] = __builtin_amdgcn_mfma_f32_16x16x32_bf16(af[i][1], bw[j][1], acc[i][j], 0, 0, 0);
      }
  }

  #pragma unroll
  for (int i = 0; i < 4; i++) {
    const int r = row0 + wm + i * 16 + quad * 4;
    #pragma unroll
    for (int j = 0; j < 4; j++) {
      const int cc = bcol0 + wn + j * 16 + l16;
      #pragma unroll
      for (int g = 0; g < 4; g++)
        Out[(size_t)(r + g) * N + cc] = acc[i][j][g];   // fp32 store
    }
  }
}

// ---------------------------------------------------------------------------
// Pass 1: per-chunk KV state S[dd][j] = sum_t phi_k[t][dd]*v[t][j] -> 64x64x64
// MFMA GEMM (contraction over t). phi already applied upstream: staging is
// pure pass-through (K^T, V^T bf16, XOR-swizzled). ksum via fp32 partials.
// ---------------------------------------------------------------------------
__global__ __launch_bounds__(256) void chunk_sums_kernel(
    const unsigned short* __restrict__ qkv,
    float* __restrict__ cs)          // [BHN*NCH][SST]
{
  const int blk = blockIdx.x;        // bh*NCH + c
  const int bh = blk >> 6, c = blk & 63;
  const int b = bh >> 2, h = bh & 3;
  __shared__ __align__(16) unsigned short sKt[64 * 64];  // K^T [dd][t] swz
  __shared__ __align__(16) unsigned short sVt[64 * 64];  // V^T [j][t]  swz
  __shared__ float sPart[4 * 64];
  const int wave = threadIdx.x >> 6, lane = threadIdx.x & 63;
  const int quad = lane >> 4, l16 = lane & 15;
  const size_t rowbase = ((size_t)b * T_SEQ + (size_t)c * CH) * NQKV + h * DH;

  float kacc = 0.f;
  #pragma unroll 4
  for (int tt = 0; tt < 16; tt++) {
    const int t = tt * 4 + wave;
    const unsigned short* r = qkv + rowbase + (size_t)t * NQKV;
    const unsigned short ku = r[256 + lane];
    const unsigned short vu = r[512 + lane];
    kacc += bf2f(ku);
    const int sw = (lane & 7) << 3;
    sKt[lane * 64 + (t ^ sw)] = ku;         // K^T: row=dd(=lane), col=t
    sVt[lane * 64 + (t ^ sw)] = vu;         // V^T: row=j (=lane), col=t
  }
  sPart[wave * 64 + lane] = kacc;
  __syncthreads();

  const int wr = (wave >> 1) * 32;   // dd offset
  const int wc = (wave & 1) * 32;    // j offset
  f32x4 acc[2][2];
  #pragma unroll
  for (int i = 0; i < 2; i++)
    #pragma unroll
    for (int j = 0; j < 2; j++) acc[i][j] = (f32x4){0.f, 0.f, 0.f, 0.f};

  #pragma unroll
  for (int ks = 0; ks < 2; ks++) {       // contraction over t (2 x K=32)
    const int grp = ks * 4 + quad;
    s16x8 ak[2], bv[2];
    #pragma unroll
    for (int i = 0; i < 2; i++) {
      const int rk = wr + i * 16 + l16;
      ak[i] = *(const s16x8*)(sKt + rk * 64 + ((grp ^ (rk & 7)) << 3));
    }
    #pragma unroll
    for (int j = 0; j < 2; j++) {
      const int rj = wc + j * 16 + l16;
      bv[j] = *(const s16x8*)(sVt + rj * 64 + ((grp ^ (rj & 7)) << 3));
    }
    #pragma unroll
    for (int i = 0; i < 2; i++)
      #pragma unroll
      for (int j = 0; j < 2; j++)
        acc[i][j] = __builtin_amdgcn_mfma_f32_16x16x32_bf16(ak[i], bv[j], acc[i][j], 0, 0, 0);
  }

  float* o = cs + (size_t)blk * SST;
  #pragma unroll
  for (int i = 0; i < 2; i++)
    #pragma unroll
    for (int j = 0; j < 2; j++)
      #pragma unroll
      for (int g = 0; g < 4; g++) {
        const int dd = wr + i * 16 + quad * 4 + g;
        const int jj = wc + j * 16 + l16;
        o[dd * 64 + jj] = acc[i][j][g];
      }
  if (threadIdx.x < 64)
    o[4096 + threadIdx.x] = sPart[threadIdx.x] + sPart[64 + threadIdx.x]
                          + sPart[128 + threadIdx.x] + sPart[192 + threadIdx.x];
}

// ---------------------------------------------------------------------------
// Pass 2: exclusive prefix scan over chunks, in-place. Emits kv_f, kc_f as
// FP32 to the output tail (float offsets!).
// ---------------------------------------------------------------------------
__global__ __launch_bounds__(256) void scan_kernel(
    float* __restrict__ cs, float* __restrict__ outTail)
{
  const int gid = blockIdx.x * 256 + threadIdx.x;   // BHN*SST threads
  const int bh = gid / SST;
  const int e  = gid - bh * SST;
  float run = 0.f;
  size_t idx = (size_t)bh * NCH * SST + e;
  for (int c = 0; c < NCH; c++, idx += SST) {
    const float v = cs[idx];
    cs[idx] = run;
    run += v;
  }
  if (e < 4096) {          // kv_f[b,h,j,dd] = state[dd][j] (transpose)
    const int dd = e >> 6, j = e & 63;
    outTail[(size_t)bh * 4096 + j * 64 + dd] = run;
  } else {                 // kc_f[b,h,dd]
    const int dd = e - 4096;
    outTail[BHN * 4096 + (size_t)bh * 64 + dd] = run;
  }
}

// ---------------------------------------------------------------------------
// Pass 3 (MFMA): per-chunk outputs. phi already applied upstream.
//   A   = tril(Q K^T)                       -> phase A MFMA, masked, bf16 LDS
//   num = Q @ S0 + A @ V                    -> phase B MFMA (one accumulator)
//   den = q . kc0 + rowsum(tril A) + eps    -> cheap VALU pass from bf16 A
//   y_att = num/den -> bf16 [MR][256]
// Q,K staged via global_load_lds (pre-swizzled source col, linear dest ->
// identical LDS image to the old register path). V^T register transpose.
// ---------------------------------------------------------------------------
__global__ __launch_bounds__(256, 4) void chunk_out_kernel(
    const unsigned short* __restrict__ qkv,
    const float* __restrict__ st,
    unsigned short* __restrict__ yatt)
{
  const int blk = blockIdx.x;
  const int bh = blk >> 6;
  const int c  = blk & 63;
  const int b = bh >> 2, h = bh & 3;

  __shared__ __align__(16) unsigned short sQ [64 * 64];  // Q  [t][d]  bf16 swz
  __shared__ __align__(16) unsigned short sKA[64 * 64];  // K  [s][d], then A [t][s]
  __shared__ __align__(16) unsigned short sVt[64 * 64];  // V^T[j][t]  bf16 swz
  __shared__ __align__(16) unsigned short sSt[64 * 64];  // S^T[j][d]  bf16 swz
  __shared__ float sKc[64];
  __shared__ float sDen[64];

  const int tid  = threadIdx.x;
  const int wave = tid >> 6, lane = tid & 63;
  const int quad = lane >> 4, l16 = lane & 15;
  const size_t rowbase = ((size_t)b * T_SEQ + (size_t)c * CH) * NQKV + h * DH;

  // ---- stage: Q,K async via global_load_lds (2 passes each) ----
  #pragma unroll
  for (int p = 0; p < 2; p++) {
    const int e  = p * 2048 + tid * 8;       // dest elem (linear = swz layout)
    const int t  = e >> 6;
    const int c0 = e & 56;                   // 8-aligned col within row
    const int sc = c0 ^ ((t & 7) << 3);      // source col (involution)
    const unsigned short* src = qkv + rowbase + (size_t)t * NQKV + sc;
    gl_lds16(src,       sQ  + e);
    gl_lds16(src + 256, sKA + e);
  }
  // ---- V^T register transpose (pass-through bf16) ----
  #pragma unroll 4
  for (int tt = 0; tt < 16; tt++) {
    const int t = tt * 4 + wave;
    sVt[lane * 64 + (t ^ ((lane & 7) << 3))] =
        qkv[rowbase + (size_t)t * NQKV + 512 + lane];
  }
  // state S[d][j] fp32 -> sSt[j][d] bf16 (transposed, swizzled); kc fp32
  const float* stp = st + (size_t)blk * SST;
  for (int i = tid; i < 1024; i += 256) {
    const f32x4 s4 = ((const f32x4*)stp)[i];
    const int d = i >> 4, j0 = (i & 15) << 2;
    #pragma unroll
    for (int g = 0; g < 4; g++) {
      const int j = j0 + g;
      sSt[j * 64 + (d ^ ((j & 7) << 3))] = f2bf(s4[g]);
    }
  }
  if (tid < 64) sKc[tid] = stp[4096 + tid];
  __syncthreads();   // drains vmcnt (gl_lds) + lgkmcnt

  // wave -> 32x32 output quadrant
  const int wr = (wave >> 1) * 32;   // t offset
  const int wc = (wave & 1) * 32;    // s / j offset

  // ---- phase A: A = Q K^T (contraction over d) ----
  f32x4 accA[2][2];
  #pragma unroll
  for (int i = 0; i < 2; i++)
    #pragma unroll
    for (int j = 0; j < 2; j++) accA[i][j] = (f32x4){0.f, 0.f, 0.f, 0.f};

  #pragma unroll
  for (int ks = 0; ks < 2; ks++) {
    const int grp = ks * 4 + quad;
    s16x8 aq[2], bk[2];
    #pragma unroll
    for (int i = 0; i < 2; i++) {
      const int rq = wr + i * 16 + l16;
      aq[i] = *(const s16x8*)(sQ + rq * 64 + ((grp ^ (rq & 7)) << 3));
    }
    #pragma unroll
    for (int j = 0; j < 2; j++) {
      const int rk = wc + j * 16 + l16;
      bk[j] = *(const s16x8*)(sKA + rk * 64 + ((grp ^ (rk & 7)) << 3));
    }
    #pragma unroll
    for (int i = 0; i < 2; i++)
      #pragma unroll
      for (int j = 0; j < 2; j++)
        accA[i][j] = __builtin_amdgcn_mfma_f32_16x16x32_bf16(aq[i], bk[j], accA[i][j], 0, 0, 0);
  }
  __syncthreads();   // all waves done reading K -> safe to overwrite with A

  // causal mask + store A (bf16, swizzled) into sKA
  #pragma unroll
  for (int i = 0; i < 2; i++)
    #pragma unroll
    for (int j = 0; j < 2; j++)
      #pragma unroll
      for (int g = 0; g < 4; g++) {
        const int t = wr + i * 16 + quad * 4 + g;
        const int s = wc + j * 16 + l16;
        const float av = (s <= t) ? accA[i][j][g] : 0.f;
        sKA[t * 64 + (s ^ ((t & 7) << 3))] = f2bf(av);
      }
  __syncthreads();

  // ---- den[t] = q.kc + rowsum(tril A) + eps (4 threads per row) ----
  {
    const int t = tid >> 2, p = tid & 3;
    const int sw = (t & 7) << 3;
    float s = 0.f;
    #pragma unroll
    for (int e = 0; e < 16; e++) {
      const int d = p * 16 + e;
      s += bf2f(sKA[t * 64 + d]);                      // swizzle is a row permutation
      s += bf2f(sQ[t * 64 + (d ^ sw)]) * sKc[d];
    }
    s += __shfl_xor(s, 1, 64);
    s += __shfl_xor(s, 2, 64);
    if (p == 0) sDen[t] = s + 1e-6f;
  }
  __syncthreads();

  // ---- phase B: num = Q @ S^T^T + A @ V^T^T (one accumulator) ----
  f32x4 acc[2][2];
  #pragma unroll
  for (int i = 0; i < 2; i++)
    #pragma unroll
    for (int j = 0; j < 2; j++) acc[i][j] = (f32x4){0.f, 0.f, 0.f, 0.f};

  #pragma unroll
  for (int ks = 0; ks < 2; ks++) {        // B1: contraction over d
    const int grp = ks * 4 + quad;
    s16x8 aq[2], bs[2];
    #pragma unroll
    for (int i = 0; i < 2; i++) {
      const int rq = wr + i * 16 + l16;
      aq[i] = *(const s16x8*)(sQ + rq * 64 + ((grp ^ (rq & 7)) << 3));
    }
    #pragma unroll
    for (int j = 0; j < 2; j++) {
      const int rj = wc + j * 16 + l16;
      bs[j] = *(const s16x8*)(sSt + rj * 64 + ((grp ^ (rj & 7)) << 3));
    }
    #pragma unroll
    for (int i = 0; i < 2; i++)
      #pragma unroll
      for (int j = 0; j < 2; j++)
        acc[i][j] = __builtin_amdgcn_mfma_f32_16x16x32_bf16(aq[i], bs[j], acc[i][j], 0, 0, 0);
  }
  #pragma unroll
  for (int ks = 0; ks < 2; ks++) {        // B2: contraction over s
    const int grp = ks * 4 + quad;
    s16x8 aa[2], bv[2];
    #pragma unroll
    for (int i = 0; i < 2; i++) {
      const int rt = wr + i * 16 + l16;
      aa[i] = *(const s16x8*)(sKA + rt * 64 + ((grp ^ (rt & 7)) << 3));
    }
    #pragma unroll
    for (int j = 0; j < 2; j++) {
      const int rj = wc + j * 16 + l16;
      bv[j] = *(const s16x8*)(sVt + rj * 64 + ((grp ^ (rj & 7)) << 3));
    }
    #pragma unroll
    for (int i = 0; i < 2; i++)
      #pragma unroll
      for (int j = 0; j < 2; j++)
        acc[i][j] = __builtin_amdgcn_mfma_f32_16x16x32_bf16(aa[i], bv[j], acc[i][j], 0, 0, 0);
  }

  // ---- epilogue: y = num / den -> bf16 ----
  #pragma unroll
  for (int i = 0; i < 2; i++)
    #pragma unroll
    for (int g = 0; g < 4; g++) {
      const int t = wr + i * 16 + quad * 4 + g;
      const float inv = 1.f / sDen[t];
      #pragma unroll
      for (int j = 0; j < 2; j++) {
        const int jj = wc + j * 16 + l16;
        const size_t o = ((size_t)b * T_SEQ + (size_t)c * CH + t) * 256 + h * 64 + jj;
        yatt[o] = f2bf(acc[i][j][g] * inv);
      }
    }
}

// ---------------------------------------------------------------------------
extern "C" void kernel_launch(void* const* d_in, const int* in_sizes, int n_in,
                              void* d_out, int out_size, void* d_ws, size_t ws_size,
                              hipStream_t stream) {
  const float* X  = (const float*)d_in[0];
  const float* Wq = (const float*)d_in[1];
  const float* Wk = (const float*)d_in[2];
  const float* Wv = (const float*)d_in[3];
  const float* Wo = (const float*)d_in[4];
  float* out = (float*)d_out;                        // FP32 output buffer

  // scratch parked inside d_out's fp32 y region (64MB), overwritten by
  // gemm_out last (gemm_out reads only d_ws -> no race):
  unsigned short* qkvb = (unsigned short*)d_out;                          // 25.2MB
  unsigned short* Xb   = (unsigned short*)((char*)d_out + 25165824ull);   // 32MB
  unsigned short* Wb   = Xb + 16777216;                                   // 1.5MB
  float* outTail = out + 16777216;                   // kv_f then kc_f (fp32)
  float*          cs   = (float*)d_ws;               // 17.04MB
  unsigned short* yatt = (unsigned short*)((char*)d_ws + 17039360ull);  // 8.39MB
  // WoB (bf16 Wo, 512KB) reuses the cs region -- dead after chunk_out.
  unsigned short* WoB  = (unsigned short*)d_ws;

  convert_kernel   <<<4096,         256, 0, stream>>>(X, Wq, Wk, Wv, Xb, Wb);
  gemm_qkv_kernel  <<<dim3(128, 6), 256, 0, stream>>>(Xb, Wb, qkvb);
  chunk_sums_kernel<<<BHN * NCH,    256, 0, stream>>>(qkvb, cs);
  scan_kernel      <<<(BHN * SST) / 256, 256, 0, stream>>>(cs, outTail);
  chunk_out_kernel <<<BHN * NCH,    256, 0, stream>>>(qkvb, cs, yatt);
  convert_wo_kernel<<<128,          256, 0, stream>>>(Wo, WoB);
  gemm_out_kernel  <<<dim3(128, 8), 256, 0, stream>>>(yatt, WoB, out);
}